// Round 21
// baseline (153.893 us; speedup 1.0000x reference)
//
#include <hip/hip_runtime.h>
#include <hip/hip_bf16.h>
#include <cmath>

#define D_MODEL 1024
#define NH 16
#define HD 64
#define BSZ 2
#define SEQ 2048
#define MTOT (BSZ * SEQ)   // 4096

typedef _Float16 f16x8 __attribute__((ext_vector_type(8)));
typedef __fp16   fp16x2 __attribute__((ext_vector_type(2)));  // cvt_pkrtz result type
typedef float    f32x4  __attribute__((ext_vector_type(4)));
typedef float    f32x16 __attribute__((ext_vector_type(16)));
typedef unsigned int uivec2 __attribute__((ext_vector_type(2)));

// Q pre-scale: (1/sqrt(64)) * log2(e)  -> softmax runs in exp2 domain
#define QSCALE 0.18033688011112042f

__device__ __forceinline__ ushort f2h(float x) {
    union { _Float16 h; ushort u; } cv;
    cv.h = (_Float16)x;
    return cv.u;
}
__device__ __forceinline__ uint pkh(float a, float b) {   // pack 2 f32 -> 2 f16
    union { fp16x2 h; uint u; } cv;
    cv.h = __builtin_amdgcn_cvt_pkrtz(a, b);
    return cv.u;
}
__device__ __forceinline__ float fexp2(float x) {
    float r; asm("v_exp_f32 %0, %1" : "=v"(r) : "v"(x)); return r;
}
__device__ __forceinline__ float fmax3(float a, float b, float c) {
    return fmaxf(fmaxf(a, b), c);   // clang fuses to v_max3_f32
}
// async global->LDS, 16B/lane; lds base wave-uniform, data lands at base+lane*16
__device__ __forceinline__ void gload_lds16(const ushort* g, ushort* l) {
    __builtin_amdgcn_global_load_lds(
        (const __attribute__((address_space(1))) void*)g,
        (__attribute__((address_space(3))) void*)l, 16, 0, 0);
}

// ---------------------------------------------------------------------------
// Fused prep (r15, measured-best; HBM-bound ~11 us): blocks [0,2048) cast x
// fp32 -> f16; blocks [2048,6144) transpose+cast weights -> [C][1024] f16.
// ---------------------------------------------------------------------------
__global__ __launch_bounds__(256)
void prep_fused(const float* __restrict__ x, const float* __restrict__ Wq,
                const float* __restrict__ Wp, ushort* __restrict__ Xh,
                ushort* __restrict__ WqT, ushort* __restrict__ WpT)
{
    const int b = blockIdx.x;
    if (b < 2048) {                       // cast slab: 2048*256*8 = 4M elems
        const int i = (b * 256 + threadIdx.x) * 8;
        float4 a  = *(const float4*)(x + i);
        float4 c4 = *(const float4*)(x + i + 4);
        alignas(16) ushort h8[8];
        h8[0] = f2h(a.x);  h8[1] = f2h(a.y);  h8[2] = f2h(a.z);  h8[3] = f2h(a.w);
        h8[4] = f2h(c4.x); h8[5] = f2h(c4.y); h8[6] = f2h(c4.z); h8[7] = f2h(c4.w);
        *(uint4*)(Xh + i) = *(const uint4*)h8;
        return;
    }
    __shared__ float tile[32][33];
    const int bt = b - 2048;
    const float* in; ushort* out; int C, cb, rb;
    if (bt < 3072) { in = Wq; out = WqT; C = 3 * D_MODEL; cb = bt % 96; rb = bt / 96; }
    else { const int b2 = bt - 3072; in = Wp; out = WpT; C = D_MODEL; cb = b2 & 31; rb = b2 >> 5; }
    const int t  = threadIdx.x;
    const int r0 = rb * 32, c0 = cb * 32;
    const int tr = t >> 5, tc = t & 31;   // 8 x 32
#pragma unroll
    for (int s = 0; s < 4; ++s)
        tile[tr + 8 * s][tc] = in[(size_t)(r0 + tr + 8 * s) * C + c0 + tc];
    __syncthreads();
#pragma unroll
    for (int s = 0; s < 4; ++s)
        out[(size_t)(c0 + tr + 8 * s) * D_MODEL + r0 + tc] = f2h(tile[tc][tr + 8 * s]);
}

// ---------------------------------------------------------------------------
// MFMA GEMM, 64x128 tile (r20, passing): 4 waves 2x2, wave tile 32x64,
// 3 LDS buffers (BK=32), single-barrier counted-vmcnt (steady vmcnt(3)).
// MODE 0: QKV scatter -> f16 Q/K [B][H][T][64] (Q scaled), V -> Vt [B][H][64][T]
// MODE 1: fp32 row-major out [M][N]
// ---------------------------------------------------------------------------
template <int MODE>
__global__ __launch_bounds__(256)
void gemm_mfma(const ushort* __restrict__ A, const ushort* __restrict__ Bt,
               float* __restrict__ outp,
               ushort* __restrict__ Qw, ushort* __restrict__ Kw,
               ushort* __restrict__ Vw, int N)
{
    __shared__ ushort As[3][64 * 32];    // [buf][row][k], 4 KB each
    __shared__ ushort Bs[3][128 * 32];   // 8 KB each

    const int t  = threadIdx.x;
    const int w  = t >> 6;
    const int l  = t & 63;
    const int lr = l & 15;
    const int lg = l >> 4;
    const int wr = w >> 1, wc = w & 1;
    const int m0 = blockIdx.y * 64, n0 = blockIdx.x * 128;

    const ushort* Ab = A  + (size_t)m0 * 1024;
    const ushort* Bb = Bt + (size_t)n0 * 1024;

    f32x4 acc[2][4];
#pragma unroll
    for (int i = 0; i < 2; ++i)
#pragma unroll
        for (int j = 0; j < 4; ++j) acc[i][j] = (f32x4){0.f, 0.f, 0.f, 0.f};

    auto stage = [&](int buf, int kt) {
        const int k0 = kt * 32;
        {
            const int c = w * 64 + l;
            gload_lds16(Ab + (size_t)(c >> 2) * 1024 + k0 + (c & 3) * 8,
                        &As[buf][(w * 64) * 8]);
        }
#pragma unroll
        for (int s = 0; s < 2; ++s) {
            const int c = w * 128 + s * 64 + l;
            gload_lds16(Bb + (size_t)(c >> 2) * 1024 + k0 + (c & 3) * 8,
                        &Bs[buf][(w * 128 + s * 64) * 8]);
        }
    };

    auto body = [&](int kt, int cb, int vm) {
        if (vm == 3) asm volatile("s_waitcnt vmcnt(3)" ::: "memory");
        else         asm volatile("s_waitcnt vmcnt(0)" ::: "memory");
        __builtin_amdgcn_s_barrier();      // tile kt in LDS; kt-1 reads retired
        if (kt + 2 < 32) stage((cb + 2) % 3, kt + 2);   // WAR-safe after barrier

        f16x8 af[2], bf[4];
#pragma unroll
        for (int m = 0; m < 2; ++m)
            af[m] = *(const f16x8*)&As[cb][(wr * 32 + m * 16 + lr) * 32 + lg * 8];
#pragma unroll
        for (int n = 0; n < 4; ++n)
            bf[n] = *(const f16x8*)&Bs[cb][(wc * 64 + n * 16 + lr) * 32 + lg * 8];
        __builtin_amdgcn_s_setprio(1);
#pragma unroll
        for (int m = 0; m < 2; ++m)
#pragma unroll
            for (int n = 0; n < 4; ++n)
                acc[m][n] = __builtin_amdgcn_mfma_f32_16x16x32_f16(
                    af[m], bf[n], acc[m][n], 0, 0, 0);
        __builtin_amdgcn_s_setprio(0);
    };

    stage(0, 0);
    stage(1, 1);
#pragma unroll 1
    for (int i = 0; i < 10; ++i) {      // kt = 0..29
        body(i * 3 + 0, 0, 3);
        body(i * 3 + 1, 1, 3);
        body(i * 3 + 2, 2, 3);
    }
    body(30, 0, 3);
    body(31, 1, 0);

    if (MODE == 1) {
#pragma unroll
        for (int mf = 0; mf < 2; ++mf) {
            const int row = m0 + wr * 32 + mf * 16 + lg * 4;
#pragma unroll
            for (int nf = 0; nf < 4; ++nf) {
                const int col = n0 + wc * 64 + nf * 16 + lr;
#pragma unroll
                for (int i = 0; i < 4; ++i)
                    outp[(size_t)(row + i) * N + col] = acc[mf][nf][i];
            }
        }
    } else {
#pragma unroll
        for (int mf = 0; mf < 2; ++mf) {
            const int row = m0 + wr * 32 + mf * 16 + lg * 4;
            const int b   = row >> 11;
            const int tt0 = row & (SEQ - 1);
#pragma unroll
            for (int nf = 0; nf < 4; ++nf) {
                const int col   = n0 + wc * 64 + nf * 16 + lr;
                const int which = col >> 10;
                const int h     = (col >> 6) & 15;
                const int d     = col & 63;
                if (which == 2) {
                    ushort* p = Vw + (((size_t)(b * NH + h) * HD + d) * SEQ) + tt0;
                    alignas(8) ushort e4[4];
#pragma unroll
                    for (int i = 0; i < 4; ++i) e4[i] = f2h(acc[mf][nf][i]);
                    *(uint2*)p = *(const uint2*)e4;
                } else {
                    ushort* dst = (which == 0) ? Qw : Kw;
                    const float sc = (which == 0) ? QSCALE : 1.0f;
#pragma unroll
                    for (int i = 0; i < 4; ++i)
                        dst[((size_t)(b * NH + h) * SEQ + tt0 + i) * HD + d] =
                            f2h(acc[mf][nf][i] * sc);
                }
            }
        }
    }
}

// ---------------------------------------------------------------------------
// Split-K swapped-operand MFMA flash attention, v9:
// K read DIRECTLY from global (L2-resident via bh-clustered XCD swizzle;
// A-frag = contiguous 16B/lane, no swizzle needed) -> K LDS + stageK deleted.
// LDS 64 -> 34 KB: Vt double-buffer per group (32 KB) + 2 KB m/l scratch.
// More resident blocks/CU; K path barrier-free; V DMA prefetch unchanged
// (K loads are newer vmcnt entries -> waiting for K never drains V).
// Block = 512 threads = 2 wave-groups x 4 waves; group g owns keys
// [g*1024,(g+1)*1024); in-block LDS split-K combine (oex aliased on Vt).
// C/D layout (m74/m101): col=lane&31, row=(reg&3)+8*(reg>>2)+4*(lane>>5).
// ---------------------------------------------------------------------------
__global__ __launch_bounds__(512)
void attn_mfma9(const ushort* __restrict__ Qw, const ushort* __restrict__ Kw,
                const ushort* __restrict__ Vtg, ushort* __restrict__ AO)
{
    __shared__ ushort VtAll[2][2][64 * 64];   // [group][buf] 32 KB, V^T swizzled
    __shared__ float  mlex[512];              // m[4][64] + l[4][64] scratch

    const int t    = threadIdx.x;
    const int w    = t >> 6;     // 0..7
    const int l    = t & 63;
    const int q    = l & 31;     // lane's q column
    const int hi   = l >> 5;     // 0/1
    const int half = w >> 2;     // KV half
    const int ww   = w & 3;      // wave-in-group

    // T1: bh-clustered XCD swizzle (512 = 8 x 64, bijective)
    const int lin = blockIdx.y * 16 + blockIdx.x;
    const int id2 = (lin & 7) * 64 + (lin >> 3);
    const int bh  = id2 >> 4;
    const int q0  = (id2 & 15) * 128 + ww * 32;

    const int kbase = half * (SEQ / 2);
    const int NT = (SEQ / 2) / 64;   // 16 tiles per group

    const ushort* Qp = Qw  + (size_t)bh * SEQ * HD;
    const ushort* Kp = Kw  + (size_t)bh * SEQ * HD;
    const ushort* Vp = Vtg + (size_t)bh * HD * SEQ;   // [d][key] d-major

    ushort (*Vt)[64 * 64] = VtAll[half];

    // Q B-frags: qf[kc] = Q[q0+q][kc*16 + hi*8 + (0..7)]
    f16x8 qf[4];
#pragma unroll
    for (int kc = 0; kc < 4; ++kc)
        qf[kc] = *(const f16x8*)(Qp + (size_t)(q0 + q) * HD + kc * 16 + hi * 8);

    f32x16 oacc[2];
#pragma unroll
    for (int db = 0; db < 2; ++db)
#pragma unroll
        for (int r = 0; r < 16; ++r) oacc[db][r] = 0.f;
    float m_run = -3.0e38f, l_run = 0.f;

    // V staging: linear dest, inverse-swizzled source (proven pattern).
    auto stageV = [&](int buf, int k0) {
#pragma unroll
        for (int s = 0; s < 2; ++s) {
            const int c    = ww * 64 + l + 256 * s;
            const int row  = c >> 3;                 // d row
            const int unit = (c & 7) ^ (row & 7);
            gload_lds16(Vp + (size_t)row * SEQ + k0 + unit * 8,
                        &Vt[buf][(ww * 64 + 256 * s) * 8]);
        }
    };

    // K row base for this lane's two A-frag rows (keys kb*32 + q)
    const ushort* Krow0 = Kp + (size_t)q * HD + hi * 8;

    stageV(0, kbase);
    __syncthreads();

    int cur = 0;
    for (int kt = 0; kt < NT; ++kt) {
        if (kt + 1 < NT)                 // issue next V-tile DMA before compute
            stageV(cur ^ 1, kbase + (kt + 1) * 64);

        const int k0 = kbase + kt * 64;

        // ---- S^T = K . Q^T  (K direct from global/L2) ----
        f32x16 sacc[2];
#pragma unroll
        for (int kb = 0; kb < 2; ++kb) {
            const ushort* kr = Krow0 + (size_t)(k0 + kb * 32) * HD;
            f16x8 kf[4];
#pragma unroll
            for (int kc = 0; kc < 4; ++kc)
                kf[kc] = *(const f16x8*)(kr + kc * 16);
            f32x16 a;
#pragma unroll
            for (int r = 0; r < 16; ++r) a[r] = 0.f;
            __builtin_amdgcn_s_setprio(1);
#pragma unroll
            for (int kc = 0; kc < 4; ++kc)
                a = __builtin_amdgcn_mfma_f32_32x32x16_f16(kf[kc], qf[kc], a, 0, 0, 0);
            __builtin_amdgcn_s_setprio(0);
            sacc[kb] = a;
        }

        // ---- in-lane online softmax (exp2), max3 tree + defer-max ----
        float p0 = fmax3(fmaxf(sacc[0][0], sacc[1][0]),
                         fmaxf(sacc[0][1], sacc[1][1]),
                         fmaxf(sacc[0][2], sacc[1][2]));
        float p1 = fmax3(fmaxf(sacc[0][3], sacc[1][3]),
                         fmaxf(sacc[0][4], sacc[1][4]),
                         fmaxf(sacc[0][5], sacc[1][5]));
        float p2 = fmax3(fmaxf(sacc[0][6], sacc[1][6]),
                         fmaxf(sacc[0][7], sacc[1][7]),
                         fmaxf(sacc[0][8], sacc[1][8]));
        float p3 = fmax3(fmaxf(sacc[0][9], sacc[1][9]),
                         fmaxf(sacc[0][10], sacc[1][10]),
                         fmaxf(sacc[0][11], sacc[1][11]));
        float p4 = fmax3(fmaxf(sacc[0][12], sacc[1][12]),
                         fmaxf(sacc[0][13], sacc[1][13]),
                         fmaxf(sacc[0][14], sacc[1][14]));
        float p5 = fmaxf(sacc[0][15], sacc[1][15]);
        float mx = fmaxf(fmax3(p0, p1, p2), fmax3(p3, p4, p5));
        mx = fmaxf(mx, __shfl_xor(mx, 32));   // combine partner half-row

        if (__any(mx > m_run + 8.0f)) {    // rescale only when max grew enough
            const float m_new = fmaxf(m_run, mx);
            const float scale = fexp2(m_run - m_new);
            m_run = m_new;
            l_run *= scale;
#pragma unroll
            for (int db = 0; db < 2; ++db)
#pragma unroll
                for (int r = 0; r < 16; ++r) oacc[db][r] *= scale;
        }

#pragma unroll
        for (int kb = 0; kb < 2; ++kb)
#pragma unroll
            for (int r = 0; r < 16; ++r)
                sacc[kb][r] = fexp2(sacc[kb][r] - m_run);

        float ts[16];
#pragma unroll
        for (int r = 0; r < 16; ++r) ts[r] = sacc[0][r] + sacc[1][r];
#pragma unroll
        for (int s = 8; s > 0; s >>= 1)
#pragma unroll
            for (int r = 0; r < 8; ++r)
                if (r < s) ts[r] += ts[r + s];
        l_run += ts[0] + __shfl_xor(ts[0], 32);

        // ---- pack P^T frags: cvt_pkrtz + permlane32_swap ----
        f16x8 pfrag[4];
#pragma unroll
        for (int kb = 0; kb < 2; ++kb)
#pragma unroll
            for (int lc = 0; lc < 2; ++lc) {
                const int rb = lc * 8;
                uint a = pkh(sacc[kb][rb + 0], sacc[kb][rb + 1]);
                uint b = pkh(sacc[kb][rb + 2], sacc[kb][rb + 3]);
                uint c = pkh(sacc[kb][rb + 4], sacc[kb][rb + 5]);
                uint d = pkh(sacc[kb][rb + 6], sacc[kb][rb + 7]);
                uivec2 r0 = __builtin_amdgcn_permlane32_swap(a, c, false, false);
                uivec2 r1 = __builtin_amdgcn_permlane32_swap(b, d, false, false);
                union { uint u[4]; f16x8 v; } f;
                f.u[0] = r0.x;
                f.u[1] = r1.x;
                f.u[2] = r0.y;
                f.u[3] = r1.y;
                pfrag[kb * 2 + lc] = f.v;
            }

        // ---- O^T += V^T . P^T  (proven swizzled ds_read_b128 path) ----
        __builtin_amdgcn_s_setprio(1);
#pragma unroll
        for (int db = 0; db < 2; ++db) {
            const int row = db * 32 + q;
            const int swz = (row & 7) << 4;
#pragma unroll
            for (int kc = 0; kc < 4; ++kc) {
                f16x8 vf = *(const f16x8*)(
                    (const char*)Vt[cur] + row * 128 + ((kc * 32 + hi * 16) ^ swz));
                oacc[db] = __builtin_amdgcn_mfma_f32_32x32x16_f16(
                    vf, pfrag[kc], oacc[db], 0, 0, 0);
            }
        }
        __builtin_amdgcn_s_setprio(0);

        __syncthreads();
        cur ^= 1;
    }

    // ---- in-block split-K combine (oex aliased on retired Vt; m/l in mlex) ----
    float* oex = (float*)VtAll;            // [4][2][16][64] f32 = 32 KB exact
    float* mex = mlex;                     // [4][64]
    float* lex = mlex + 256;               // [4][64]

    if (half == 1) {
        mex[ww * 64 + l] = m_run;
        lex[ww * 64 + l] = l_run;
#pragma unroll
        for (int db = 0; db < 2; ++db)
#pragma unroll
            for (int r = 0; r < 16; ++r)
                oex[(((ww * 2 + db) * 16) + r) * 64 + l] = oacc[db][r];
    }
    __syncthreads();
    if (half == 0) {
        const float m2 = mex[ww * 64 + l];
        const float l2 = lex[ww * 64 + l];
        const float mf = fmaxf(m_run, m2);
        float w1 = fexp2(m_run - mf), w2 = fexp2(m2 - mf);
        const float inv = 1.f / (l_run * w1 + l2 * w2);
        w1 *= inv; w2 *= inv;

        const int b = bh >> 4, h = bh & 15;
        ushort* orow = AO + ((size_t)(b * SEQ) + q0 + q) * D_MODEL + h * HD;
#pragma unroll
        for (int db = 0; db < 2; ++db)
#pragma unroll
            for (int g = 0; g < 4; ++g) {
                const int d = db * 32 + g * 8 + hi * 4;
                alignas(8) ushort e4[4];
#pragma unroll
                for (int i = 0; i < 4; ++i) {
                    const float o2 = oex[(((ww * 2 + db) * 16) + g * 4 + i) * 64 + l];
                    e4[i] = f2h(oacc[db][g * 4 + i] * w1 + o2 * w2);
                }
                *(uint2*)(orow + d) = *(const uint2*)e4;
            }
    }
}

// ---------------------------------------------------------------------------
extern "C" void kernel_launch(void* const* d_in, const int* in_sizes, int n_in,
                              void* d_out, int out_size, void* d_ws, size_t ws_size,
                              hipStream_t stream)
{
    const float* x      = (const float*)d_in[0];  // (2, 2048, 1024)
    const float* w_qkv  = (const float*)d_in[1];  // (1024, 3072)
    const float* w_proj = (const float*)d_in[2];  // (1024, 1024)
    float* out = (float*)d_out;                   // (2, 2048, 1024) fp32

    ushort* Xh  = (ushort*)d_ws;                        // 4M
    ushort* WqT = Xh  + (size_t)MTOT * D_MODEL;         // 3M  [3072][1024]
    ushort* WpT = WqT + (size_t)3 * D_MODEL * D_MODEL;  // 1M  [1024][1024]
    ushort* Qw  = WpT + (size_t)D_MODEL * D_MODEL;      // 4M  [B][H][T][64]
    ushort* Kw  = Qw  + (size_t)MTOT * D_MODEL;         // 4M  [B][H][T][64]
    ushort* Vt  = Kw  + (size_t)MTOT * D_MODEL;         // 4M  [B][H][64][T]
    ushort* AOh = Vt  + (size_t)MTOT * D_MODEL;         // 4M  [B][T][D]

    dim3 blk(256);

    // 0) fused prep: x cast + both weight transposes in one launch
    prep_fused<<<dim3(2048 + 3072 + 1024), blk, 0, stream>>>(
        x, w_qkv, w_proj, Xh, WqT, WpT);

    // 1) QKV = Xh @ WqT^T (64x128 tiles, 1536 blocks)
    gemm_mfma<0><<<dim3(3 * D_MODEL / 128, MTOT / 64), blk, 0, stream>>>(
        Xh, WqT, nullptr, Qw, Kw, Vt, 3 * D_MODEL);

    // 2) split-K MFMA flash attention, K direct-from-L2
    attn_mfma9<<<dim3(SEQ / 128, BSZ * NH), dim3(512), 0, stream>>>(Qw, Kw, Vt, AOh);

    // 3) out = AOh @ WpT^T (fp32 out, 512 blocks)
    gemm_mfma<1><<<dim3(D_MODEL / 128, MTOT / 64), blk, 0, stream>>>(
        AOh, WpT, out, nullptr, nullptr, nullptr, D_MODEL);
}

// Round 22
// 131.393 us; speedup vs baseline: 1.1712x; 1.1712x over previous
//
#include <hip/hip_runtime.h>
#include <hip/hip_bf16.h>
#include <cmath>

#define D_MODEL 1024
#define NH 16
#define HD 64
#define BSZ 2
#define SEQ 2048
#define MTOT (BSZ * SEQ)   // 4096

typedef _Float16 f16x8 __attribute__((ext_vector_type(8)));
typedef __fp16   fp16x2 __attribute__((ext_vector_type(2)));  // cvt_pkrtz result type
typedef float    f32x4  __attribute__((ext_vector_type(4)));
typedef float    f32x16 __attribute__((ext_vector_type(16)));
typedef unsigned int uivec2 __attribute__((ext_vector_type(2)));

// Q pre-scale: (1/sqrt(64)) * log2(e)  -> softmax runs in exp2 domain
#define QSCALE 0.18033688011112042f

__device__ __forceinline__ ushort f2h(float x) {
    union { _Float16 h; ushort u; } cv;
    cv.h = (_Float16)x;
    return cv.u;
}
__device__ __forceinline__ uint pkh(float a, float b) {   // pack 2 f32 -> 2 f16
    union { fp16x2 h; uint u; } cv;
    cv.h = __builtin_amdgcn_cvt_pkrtz(a, b);
    return cv.u;
}
__device__ __forceinline__ float fexp2(float x) {
    float r; asm("v_exp_f32 %0, %1" : "=v"(r) : "v"(x)); return r;
}
__device__ __forceinline__ float fmax3(float a, float b, float c) {
    return fmaxf(fmaxf(a, b), c);   // clang fuses to v_max3_f32
}
// async global->LDS, 16B/lane; lds base wave-uniform, data lands at base+lane*16
__device__ __forceinline__ void gload_lds16(const ushort* g, ushort* l) {
    __builtin_amdgcn_global_load_lds(
        (const __attribute__((address_space(1))) void*)g,
        (__attribute__((address_space(3))) void*)l, 16, 0, 0);
}

// ---------------------------------------------------------------------------
// Fused prep (r15, measured-best; HBM-bound ~11 us): blocks [0,2048) cast x
// fp32 -> f16; blocks [2048,6144) transpose+cast weights -> [C][1024] f16.
// ---------------------------------------------------------------------------
__global__ __launch_bounds__(256)
void prep_fused(const float* __restrict__ x, const float* __restrict__ Wq,
                const float* __restrict__ Wp, ushort* __restrict__ Xh,
                ushort* __restrict__ WqT, ushort* __restrict__ WpT)
{
    const int b = blockIdx.x;
    if (b < 2048) {                       // cast slab: 2048*256*8 = 4M elems
        const int i = (b * 256 + threadIdx.x) * 8;
        float4 a  = *(const float4*)(x + i);
        float4 c4 = *(const float4*)(x + i + 4);
        alignas(16) ushort h8[8];
        h8[0] = f2h(a.x);  h8[1] = f2h(a.y);  h8[2] = f2h(a.z);  h8[3] = f2h(a.w);
        h8[4] = f2h(c4.x); h8[5] = f2h(c4.y); h8[6] = f2h(c4.z); h8[7] = f2h(c4.w);
        *(uint4*)(Xh + i) = *(const uint4*)h8;
        return;
    }
    __shared__ float tile[32][33];
    const int bt = b - 2048;
    const float* in; ushort* out; int C, cb, rb;
    if (bt < 3072) { in = Wq; out = WqT; C = 3 * D_MODEL; cb = bt % 96; rb = bt / 96; }
    else { const int b2 = bt - 3072; in = Wp; out = WpT; C = D_MODEL; cb = b2 & 31; rb = b2 >> 5; }
    const int t  = threadIdx.x;
    const int r0 = rb * 32, c0 = cb * 32;
    const int tr = t >> 5, tc = t & 31;   // 8 x 32
#pragma unroll
    for (int s = 0; s < 4; ++s)
        tile[tr + 8 * s][tc] = in[(size_t)(r0 + tr + 8 * s) * C + c0 + tc];
    __syncthreads();
#pragma unroll
    for (int s = 0; s < 4; ++s)
        out[(size_t)(c0 + tr + 8 * s) * D_MODEL + r0 + tc] = f2h(tile[tc][tr + 8 * s]);
}

// ---------------------------------------------------------------------------
// MFMA GEMM, 64x128 tile (r20, passing): 4 waves 2x2, wave tile 32x64,
// 3 LDS buffers (BK=32), single-barrier counted-vmcnt (steady vmcnt(3)).
// MODE 0: QKV scatter -> f16 Q/K [B][H][T][64] (Q scaled), V -> Vt [B][H][64][T]
// MODE 1: fp32 row-major out [M][N]
// ---------------------------------------------------------------------------
template <int MODE>
__global__ __launch_bounds__(256)
void gemm_mfma(const ushort* __restrict__ A, const ushort* __restrict__ Bt,
               float* __restrict__ outp,
               ushort* __restrict__ Qw, ushort* __restrict__ Kw,
               ushort* __restrict__ Vw, int N)
{
    __shared__ ushort As[3][64 * 32];    // [buf][row][k], 4 KB each
    __shared__ ushort Bs[3][128 * 32];   // 8 KB each

    const int t  = threadIdx.x;
    const int w  = t >> 6;
    const int l  = t & 63;
    const int lr = l & 15;
    const int lg = l >> 4;
    const int wr = w >> 1, wc = w & 1;
    const int m0 = blockIdx.y * 64, n0 = blockIdx.x * 128;

    const ushort* Ab = A  + (size_t)m0 * 1024;
    const ushort* Bb = Bt + (size_t)n0 * 1024;

    f32x4 acc[2][4];
#pragma unroll
    for (int i = 0; i < 2; ++i)
#pragma unroll
        for (int j = 0; j < 4; ++j) acc[i][j] = (f32x4){0.f, 0.f, 0.f, 0.f};

    auto stage = [&](int buf, int kt) {
        const int k0 = kt * 32;
        {
            const int c = w * 64 + l;
            gload_lds16(Ab + (size_t)(c >> 2) * 1024 + k0 + (c & 3) * 8,
                        &As[buf][(w * 64) * 8]);
        }
#pragma unroll
        for (int s = 0; s < 2; ++s) {
            const int c = w * 128 + s * 64 + l;
            gload_lds16(Bb + (size_t)(c >> 2) * 1024 + k0 + (c & 3) * 8,
                        &Bs[buf][(w * 128 + s * 64) * 8]);
        }
    };

    auto body = [&](int kt, int cb, int vm) {
        if (vm == 3) asm volatile("s_waitcnt vmcnt(3)" ::: "memory");
        else         asm volatile("s_waitcnt vmcnt(0)" ::: "memory");
        __builtin_amdgcn_s_barrier();      // tile kt in LDS; kt-1 reads retired
        if (kt + 2 < 32) stage((cb + 2) % 3, kt + 2);   // WAR-safe after barrier

        f16x8 af[2], bf[4];
#pragma unroll
        for (int m = 0; m < 2; ++m)
            af[m] = *(const f16x8*)&As[cb][(wr * 32 + m * 16 + lr) * 32 + lg * 8];
#pragma unroll
        for (int n = 0; n < 4; ++n)
            bf[n] = *(const f16x8*)&Bs[cb][(wc * 64 + n * 16 + lr) * 32 + lg * 8];
        __builtin_amdgcn_s_setprio(1);
#pragma unroll
        for (int m = 0; m < 2; ++m)
#pragma unroll
            for (int n = 0; n < 4; ++n)
                acc[m][n] = __builtin_amdgcn_mfma_f32_16x16x32_f16(
                    af[m], bf[n], acc[m][n], 0, 0, 0);
        __builtin_amdgcn_s_setprio(0);
    };

    stage(0, 0);
    stage(1, 1);
#pragma unroll 1
    for (int i = 0; i < 10; ++i) {      // kt = 0..29
        body(i * 3 + 0, 0, 3);
        body(i * 3 + 1, 1, 3);
        body(i * 3 + 2, 2, 3);
    }
    body(30, 0, 3);
    body(31, 1, 0);

    if (MODE == 1) {
#pragma unroll
        for (int mf = 0; mf < 2; ++mf) {
            const int row = m0 + wr * 32 + mf * 16 + lg * 4;
#pragma unroll
            for (int nf = 0; nf < 4; ++nf) {
                const int col = n0 + wc * 64 + nf * 16 + lr;
#pragma unroll
                for (int i = 0; i < 4; ++i)
                    outp[(size_t)(row + i) * N + col] = acc[mf][nf][i];
            }
        }
    } else {
#pragma unroll
        for (int mf = 0; mf < 2; ++mf) {
            const int row = m0 + wr * 32 + mf * 16 + lg * 4;
            const int b   = row >> 11;
            const int tt0 = row & (SEQ - 1);
#pragma unroll
            for (int nf = 0; nf < 4; ++nf) {
                const int col   = n0 + wc * 64 + nf * 16 + lr;
                const int which = col >> 10;
                const int h     = (col >> 6) & 15;
                const int d     = col & 63;
                if (which == 2) {
                    ushort* p = Vw + (((size_t)(b * NH + h) * HD + d) * SEQ) + tt0;
                    alignas(8) ushort e4[4];
#pragma unroll
                    for (int i = 0; i < 4; ++i) e4[i] = f2h(acc[mf][nf][i]);
                    *(uint2*)p = *(const uint2*)e4;
                } else {
                    ushort* dst = (which == 0) ? Qw : Kw;
                    const float sc = (which == 0) ? QSCALE : 1.0f;
#pragma unroll
                    for (int i = 0; i < 4; ++i)
                        dst[((size_t)(b * NH + h) * SEQ + tt0 + i) * HD + d] =
                            f2h(acc[mf][nf][i] * sc);
                }
            }
        }
    }
}

// ---------------------------------------------------------------------------
// Split-K swapped-operand MFMA flash attention, v7 (r16/r18/r19/r20 proven,
// 56.2 us) + isolated z16 zero-hoist (removes 32 v_mov zero-inits per tile;
// identical arithmetic; +16 VGPR, residency unchanged).
// Block = 512 threads = 2 wave-groups x 4 waves; group g owns keys
// [g*1024,(g+1)*1024); in-block LDS split-K combine; bh-clustered XCD swizzle.
// C/D layout (m74/m101): col=lane&31, row=(reg&3)+8*(reg>>2)+4*(lane>>5).
// ---------------------------------------------------------------------------
__global__ __launch_bounds__(512, 4)
void attn_mfma7(const ushort* __restrict__ Qw, const ushort* __restrict__ Kw,
                const ushort* __restrict__ Vtg, ushort* __restrict__ AO)
{
    __shared__ ushort KsAll[2][2][64 * 64];   // [group][buf] 32 KB
    __shared__ ushort VtAll[2][2][64 * 64];   // [group][buf] 32 KB, V^T swizzled

    const int t    = threadIdx.x;
    const int w    = t >> 6;     // 0..7
    const int l    = t & 63;
    const int q    = l & 31;     // lane's q column
    const int hi   = l >> 5;     // 0/1
    const int half = w >> 2;     // KV half
    const int ww   = w & 3;      // wave-in-group

    // T1: bh-clustered XCD swizzle (512 = 8 x 64, bijective)
    const int lin = blockIdx.y * 16 + blockIdx.x;
    const int id2 = (lin & 7) * 64 + (lin >> 3);
    const int bh  = id2 >> 4;
    const int q0  = (id2 & 15) * 128 + ww * 32;

    const int kbase = half * (SEQ / 2);
    const int NT = (SEQ / 2) / 64;   // 16 tiles per group

    const ushort* Qp = Qw  + (size_t)bh * SEQ * HD;
    const ushort* Kp = Kw  + (size_t)bh * SEQ * HD;
    const ushort* Vp = Vtg + (size_t)bh * HD * SEQ;   // [d][key] d-major

    ushort (*Ks)[64 * 64] = KsAll[half];
    ushort (*Vt)[64 * 64] = VtAll[half];

    // Q B-frags: qf[kc] = Q[q0+q][kc*16 + hi*8 + (0..7)]
    f16x8 qf[4];
#pragma unroll
    for (int kc = 0; kc < 4; ++kc)
        qf[kc] = *(const f16x8*)(Qp + (size_t)(q0 + q) * HD + kc * 16 + hi * 8);

    f32x16 oacc[2];
#pragma unroll
    for (int db = 0; db < 2; ++db)
#pragma unroll
        for (int r = 0; r < 16; ++r) oacc[db][r] = 0.f;
    float m_run = -3.0e38f, l_run = 0.f;

    f32x16 z16;                         // persistent zero C-operand (hoisted)
#pragma unroll
    for (int r = 0; r < 16; ++r) z16[r] = 0.f;

    // staging: linear dest, inverse-swizzled source (proven pattern).
    auto stageK = [&](int buf, int k0) {
#pragma unroll
        for (int s = 0; s < 2; ++s) {
            const int c    = ww * 64 + l + 256 * s;
            const int row  = c >> 3;
            const int unit = (c & 7) ^ (row & 7);
            gload_lds16(Kp + (size_t)(k0 + row) * HD + unit * 8,
                        &Ks[buf][(ww * 64 + 256 * s) * 8]);
        }
    };
    auto stageV = [&](int buf, int k0) {
#pragma unroll
        for (int s = 0; s < 2; ++s) {
            const int c    = ww * 64 + l + 256 * s;
            const int row  = c >> 3;                 // d row
            const int unit = (c & 7) ^ (row & 7);
            gload_lds16(Vp + (size_t)row * SEQ + k0 + unit * 8,
                        &Vt[buf][(ww * 64 + 256 * s) * 8]);
        }
    };

    stageK(0, kbase);
    stageV(0, kbase);
    __syncthreads();

    int cur = 0;
    for (int kt = 0; kt < NT; ++kt) {
        if (kt + 1 < NT) {               // issue next-tile DMA before compute
            stageK(cur ^ 1, kbase + (kt + 1) * 64);
            stageV(cur ^ 1, kbase + (kt + 1) * 64);
        }

        // ---- S^T = K . Q^T ----
        f32x16 sacc[2];
        __builtin_amdgcn_s_setprio(1);
#pragma unroll
        for (int kb = 0; kb < 2; ++kb) {
            const int row = kb * 32 + q;
            const int swz = (row & 7) << 4;
            f16x8 kf0 = *(const f16x8*)(
                (const char*)Ks[cur] + row * 128 + ((hi * 16) ^ swz));
            f32x16 a = __builtin_amdgcn_mfma_f32_32x32x16_f16(kf0, qf[0], z16, 0, 0, 0);
#pragma unroll
            for (int kc = 1; kc < 4; ++kc) {
                f16x8 kf = *(const f16x8*)(
                    (const char*)Ks[cur] + row * 128 + ((kc * 32 + hi * 16) ^ swz));
                a = __builtin_amdgcn_mfma_f32_32x32x16_f16(kf, qf[kc], a, 0, 0, 0);
            }
            sacc[kb] = a;
        }
        __builtin_amdgcn_s_setprio(0);

        // ---- in-lane online softmax (exp2), max3 tree + defer-max ----
        float p0 = fmax3(fmaxf(sacc[0][0], sacc[1][0]),
                         fmaxf(sacc[0][1], sacc[1][1]),
                         fmaxf(sacc[0][2], sacc[1][2]));
        float p1 = fmax3(fmaxf(sacc[0][3], sacc[1][3]),
                         fmaxf(sacc[0][4], sacc[1][4]),
                         fmaxf(sacc[0][5], sacc[1][5]));
        float p2 = fmax3(fmaxf(sacc[0][6], sacc[1][6]),
                         fmaxf(sacc[0][7], sacc[1][7]),
                         fmaxf(sacc[0][8], sacc[1][8]));
        float p3 = fmax3(fmaxf(sacc[0][9], sacc[1][9]),
                         fmaxf(sacc[0][10], sacc[1][10]),
                         fmaxf(sacc[0][11], sacc[1][11]));
        float p4 = fmax3(fmaxf(sacc[0][12], sacc[1][12]),
                         fmaxf(sacc[0][13], sacc[1][13]),
                         fmaxf(sacc[0][14], sacc[1][14]));
        float p5 = fmaxf(sacc[0][15], sacc[1][15]);
        float mx = fmaxf(fmax3(p0, p1, p2), fmax3(p3, p4, p5));
        mx = fmaxf(mx, __shfl_xor(mx, 32));   // combine partner half-row

        if (__any(mx > m_run + 8.0f)) {    // rescale only when max grew enough
            const float m_new = fmaxf(m_run, mx);
            const float scale = fexp2(m_run - m_new);
            m_run = m_new;
            l_run *= scale;
#pragma unroll
            for (int db = 0; db < 2; ++db)
#pragma unroll
                for (int r = 0; r < 16; ++r) oacc[db][r] *= scale;
        }

#pragma unroll
        for (int kb = 0; kb < 2; ++kb)
#pragma unroll
            for (int r = 0; r < 16; ++r)
                sacc[kb][r] = fexp2(sacc[kb][r] - m_run);

        float ts[16];
#pragma unroll
        for (int r = 0; r < 16; ++r) ts[r] = sacc[0][r] + sacc[1][r];
#pragma unroll
        for (int s = 8; s > 0; s >>= 1)
#pragma unroll
            for (int r = 0; r < 8; ++r)
                if (r < s) ts[r] += ts[r + s];
        l_run += ts[0] + __shfl_xor(ts[0], 32);

        // ---- pack P^T frags: cvt_pkrtz + permlane32_swap ----
        f16x8 pfrag[4];
#pragma unroll
        for (int kb = 0; kb < 2; ++kb)
#pragma unroll
            for (int lc = 0; lc < 2; ++lc) {
                const int rb = lc * 8;
                uint a = pkh(sacc[kb][rb + 0], sacc[kb][rb + 1]);
                uint b = pkh(sacc[kb][rb + 2], sacc[kb][rb + 3]);
                uint c = pkh(sacc[kb][rb + 4], sacc[kb][rb + 5]);
                uint d = pkh(sacc[kb][rb + 6], sacc[kb][rb + 7]);
                uivec2 r0 = __builtin_amdgcn_permlane32_swap(a, c, false, false);
                uivec2 r1 = __builtin_amdgcn_permlane32_swap(b, d, false, false);
                union { uint u[4]; f16x8 v; } f;
                f.u[0] = r0.x;
                f.u[1] = r1.x;
                f.u[2] = r0.y;
                f.u[3] = r1.y;
                pfrag[kb * 2 + lc] = f.v;
            }

        // ---- O^T += V^T . P^T  (proven swizzled ds_read_b128 path) ----
        __builtin_amdgcn_s_setprio(1);
#pragma unroll
        for (int db = 0; db < 2; ++db) {
            const int row = db * 32 + q;
            const int swz = (row & 7) << 4;
#pragma unroll
            for (int kc = 0; kc < 4; ++kc) {
                f16x8 vf = *(const f16x8*)(
                    (const char*)Vt[cur] + row * 128 + ((kc * 32 + hi * 16) ^ swz));
                oacc[db] = __builtin_amdgcn_mfma_f32_32x32x16_f16(
                    vf, pfrag[kc], oacc[db], 0, 0, 0);
            }
        }
        __builtin_amdgcn_s_setprio(0);

        __syncthreads();
        cur ^= 1;
    }

    // ---- in-block split-K combine (reuse retired K/V LDS) ----
    float* oex = (float*)KsAll;            // [4][2][16][64] f32 = 32 KB
    float* mex = (float*)VtAll;            // [4][64]
    float* lex = mex + 256;                // [4][64]

    if (half == 1) {
        mex[ww * 64 + l] = m_run;
        lex[ww * 64 + l] = l_run;
#pragma unroll
        for (int db = 0; db < 2; ++db)
#pragma unroll
            for (int r = 0; r < 16; ++r)
                oex[(((ww * 2 + db) * 16) + r) * 64 + l] = oacc[db][r];
    }
    __syncthreads();
    if (half == 0) {
        const float m2 = mex[ww * 64 + l];
        const float l2 = lex[ww * 64 + l];
        const float mf = fmaxf(m_run, m2);
        float w1 = fexp2(m_run - mf), w2 = fexp2(m2 - mf);
        const float inv = 1.f / (l_run * w1 + l2 * w2);
        w1 *= inv; w2 *= inv;

        const int b = bh >> 4, h = bh & 15;
        ushort* orow = AO + ((size_t)(b * SEQ) + q0 + q) * D_MODEL + h * HD;
#pragma unroll
        for (int db = 0; db < 2; ++db)
#pragma unroll
            for (int g = 0; g < 4; ++g) {
                const int d = db * 32 + g * 8 + hi * 4;
                alignas(8) ushort e4[4];
#pragma unroll
                for (int i = 0; i < 4; ++i) {
                    const float o2 = oex[(((ww * 2 + db) * 16) + g * 4 + i) * 64 + l];
                    e4[i] = f2h(oacc[db][g * 4 + i] * w1 + o2 * w2);
                }
                *(uint2*)(orow + d) = *(const uint2*)e4;
            }
    }
}

// ---------------------------------------------------------------------------
extern "C" void kernel_launch(void* const* d_in, const int* in_sizes, int n_in,
                              void* d_out, int out_size, void* d_ws, size_t ws_size,
                              hipStream_t stream)
{
    const float* x      = (const float*)d_in[0];  // (2, 2048, 1024)
    const float* w_qkv  = (const float*)d_in[1];  // (1024, 3072)
    const float* w_proj = (const float*)d_in[2];  // (1024, 1024)
    float* out = (float*)d_out;                   // (2, 2048, 1024) fp32

    ushort* Xh  = (ushort*)d_ws;                        // 4M
    ushort* WqT = Xh  + (size_t)MTOT * D_MODEL;         // 3M  [3072][1024]
    ushort* WpT = WqT + (size_t)3 * D_MODEL * D_MODEL;  // 1M  [1024][1024]
    ushort* Qw  = WpT + (size_t)D_MODEL * D_MODEL;      // 4M  [B][H][T][64]
    ushort* Kw  = Qw  + (size_t)MTOT * D_MODEL;         // 4M  [B][H][T][64]
    ushort* Vt  = Kw  + (size_t)MTOT * D_MODEL;         // 4M  [B][H][64][T]
    ushort* AOh = Vt  + (size_t)MTOT * D_MODEL;         // 4M  [B][T][D]

    dim3 blk(256);

    // 0) fused prep: x cast + both weight transposes in one launch
    prep_fused<<<dim3(2048 + 3072 + 1024), blk, 0, stream>>>(
        x, w_qkv, w_proj, Xh, WqT, WpT);

    // 1) QKV = Xh @ WqT^T (64x128 tiles, 1536 blocks)
    gemm_mfma<0><<<dim3(3 * D_MODEL / 128, MTOT / 64), blk, 0, stream>>>(
        Xh, WqT, nullptr, Qw, Kw, Vt, 3 * D_MODEL);

    // 2) split-K MFMA flash attention (+ bh-clustered XCD swizzle, z16 hoist)
    attn_mfma7<<<dim3(SEQ / 128, BSZ * NH), dim3(512), 0, stream>>>(Qw, Kw, Vt, AOh);

    // 3) out = AOh @ WpT^T (fp32 out, 512 blocks)
    gemm_mfma<1><<<dim3(D_MODEL / 128, MTOT / 64), blk, 0, stream>>>(
        AOh, WpT, out, nullptr, nullptr, nullptr, D_MODEL);
}

// Round 23
// 129.804 us; speedup vs baseline: 1.1856x; 1.0122x over previous
//
#include <hip/hip_runtime.h>
#include <hip/hip_bf16.h>
#include <cmath>

#define D_MODEL 1024
#define NH 16
#define HD 64
#define BSZ 2
#define SEQ 2048
#define MTOT (BSZ * SEQ)   // 4096

typedef _Float16 f16x8 __attribute__((ext_vector_type(8)));
typedef __fp16   fp16x2 __attribute__((ext_vector_type(2)));  // cvt_pkrtz result type
typedef float    f32x4  __attribute__((ext_vector_type(4)));
typedef float    f32x16 __attribute__((ext_vector_type(16)));
typedef unsigned int uivec2 __attribute__((ext_vector_type(2)));

// Q pre-scale: (1/sqrt(64)) * log2(e)  -> softmax runs in exp2 domain
#define QSCALE 0.18033688011112042f

__device__ __forceinline__ ushort f2h(float x) {
    union { _Float16 h; ushort u; } cv;
    cv.h = (_Float16)x;
    return cv.u;
}
__device__ __forceinline__ uint pkh(float a, float b) {   // pack 2 f32 -> 2 f16
    union { fp16x2 h; uint u; } cv;
    cv.h = __builtin_amdgcn_cvt_pkrtz(a, b);
    return cv.u;
}
__device__ __forceinline__ float fexp2(float x) {
    float r; asm("v_exp_f32 %0, %1" : "=v"(r) : "v"(x)); return r;
}
__device__ __forceinline__ float fmax3(float a, float b, float c) {
    return fmaxf(fmaxf(a, b), c);   // clang fuses to v_max3_f32
}
// async global->LDS, 16B/lane; lds base wave-uniform, data lands at base+lane*16
__device__ __forceinline__ void gload_lds16(const ushort* g, ushort* l) {
    __builtin_amdgcn_global_load_lds(
        (const __attribute__((address_space(1))) void*)g,
        (__attribute__((address_space(3))) void*)l, 16, 0, 0);
}

// ---------------------------------------------------------------------------
// Fused prep (r15, measured-best; HBM-bound ~11 us): blocks [0,2048) cast x
// fp32 -> f16; blocks [2048,6144) transpose+cast weights -> [C][1024] f16.
// ---------------------------------------------------------------------------
__global__ __launch_bounds__(256)
void prep_fused(const float* __restrict__ x, const float* __restrict__ Wq,
                const float* __restrict__ Wp, ushort* __restrict__ Xh,
                ushort* __restrict__ WqT, ushort* __restrict__ WpT)
{
    const int b = blockIdx.x;
    if (b < 2048) {                       // cast slab: 2048*256*8 = 4M elems
        const int i = (b * 256 + threadIdx.x) * 8;
        float4 a  = *(const float4*)(x + i);
        float4 c4 = *(const float4*)(x + i + 4);
        alignas(16) ushort h8[8];
        h8[0] = f2h(a.x);  h8[1] = f2h(a.y);  h8[2] = f2h(a.z);  h8[3] = f2h(a.w);
        h8[4] = f2h(c4.x); h8[5] = f2h(c4.y); h8[6] = f2h(c4.z); h8[7] = f2h(c4.w);
        *(uint4*)(Xh + i) = *(const uint4*)h8;
        return;
    }
    __shared__ float tile[32][33];
    const int bt = b - 2048;
    const float* in; ushort* out; int C, cb, rb;
    if (bt < 3072) { in = Wq; out = WqT; C = 3 * D_MODEL; cb = bt % 96; rb = bt / 96; }
    else { const int b2 = bt - 3072; in = Wp; out = WpT; C = D_MODEL; cb = b2 & 31; rb = b2 >> 5; }
    const int t  = threadIdx.x;
    const int r0 = rb * 32, c0 = cb * 32;
    const int tr = t >> 5, tc = t & 31;   // 8 x 32
#pragma unroll
    for (int s = 0; s < 4; ++s)
        tile[tr + 8 * s][tc] = in[(size_t)(r0 + tr + 8 * s) * C + c0 + tc];
    __syncthreads();
#pragma unroll
    for (int s = 0; s < 4; ++s)
        out[(size_t)(c0 + tr + 8 * s) * D_MODEL + r0 + tc] = f2h(tile[tc][tr + 8 * s]);
}

// ---------------------------------------------------------------------------
// MFMA GEMM, 64x128 tile (r20, passing): 4 waves 2x2, wave tile 32x64,
// 3 LDS buffers (BK=32), single-barrier counted-vmcnt (steady vmcnt(3)).
// MODE 0: QKV scatter -> f16 Q/K [B][H][T][64] (Q scaled), V -> Vt [B][H][64][T]
// MODE 1: fp32 row-major out [M][N]
// ---------------------------------------------------------------------------
template <int MODE>
__global__ __launch_bounds__(256)
void gemm_mfma(const ushort* __restrict__ A, const ushort* __restrict__ Bt,
               float* __restrict__ outp,
               ushort* __restrict__ Qw, ushort* __restrict__ Kw,
               ushort* __restrict__ Vw, int N)
{
    __shared__ ushort As[3][64 * 32];    // [buf][row][k], 4 KB each
    __shared__ ushort Bs[3][128 * 32];   // 8 KB each

    const int t  = threadIdx.x;
    const int w  = t >> 6;
    const int l  = t & 63;
    const int lr = l & 15;
    const int lg = l >> 4;
    const int wr = w >> 1, wc = w & 1;
    const int m0 = blockIdx.y * 64, n0 = blockIdx.x * 128;

    const ushort* Ab = A  + (size_t)m0 * 1024;
    const ushort* Bb = Bt + (size_t)n0 * 1024;

    f32x4 acc[2][4];
#pragma unroll
    for (int i = 0; i < 2; ++i)
#pragma unroll
        for (int j = 0; j < 4; ++j) acc[i][j] = (f32x4){0.f, 0.f, 0.f, 0.f};

    auto stage = [&](int buf, int kt) {
        const int k0 = kt * 32;
        {
            const int c = w * 64 + l;
            gload_lds16(Ab + (size_t)(c >> 2) * 1024 + k0 + (c & 3) * 8,
                        &As[buf][(w * 64) * 8]);
        }
#pragma unroll
        for (int s = 0; s < 2; ++s) {
            const int c = w * 128 + s * 64 + l;
            gload_lds16(Bb + (size_t)(c >> 2) * 1024 + k0 + (c & 3) * 8,
                        &Bs[buf][(w * 128 + s * 64) * 8]);
        }
    };

    auto body = [&](int kt, int cb, int vm) {
        if (vm == 3) asm volatile("s_waitcnt vmcnt(3)" ::: "memory");
        else         asm volatile("s_waitcnt vmcnt(0)" ::: "memory");
        __builtin_amdgcn_s_barrier();      // tile kt in LDS; kt-1 reads retired
        if (kt + 2 < 32) stage((cb + 2) % 3, kt + 2);   // WAR-safe after barrier

        f16x8 af[2], bf[4];
#pragma unroll
        for (int m = 0; m < 2; ++m)
            af[m] = *(const f16x8*)&As[cb][(wr * 32 + m * 16 + lr) * 32 + lg * 8];
#pragma unroll
        for (int n = 0; n < 4; ++n)
            bf[n] = *(const f16x8*)&Bs[cb][(wc * 64 + n * 16 + lr) * 32 + lg * 8];
        __builtin_amdgcn_s_setprio(1);
#pragma unroll
        for (int m = 0; m < 2; ++m)
#pragma unroll
            for (int n = 0; n < 4; ++n)
                acc[m][n] = __builtin_amdgcn_mfma_f32_16x16x32_f16(
                    af[m], bf[n], acc[m][n], 0, 0, 0);
        __builtin_amdgcn_s_setprio(0);
    };

    stage(0, 0);
    stage(1, 1);
#pragma unroll 1
    for (int i = 0; i < 10; ++i) {      // kt = 0..29
        body(i * 3 + 0, 0, 3);
        body(i * 3 + 1, 1, 3);
        body(i * 3 + 2, 2, 3);
    }
    body(30, 0, 3);
    body(31, 1, 0);

    if (MODE == 1) {
#pragma unroll
        for (int mf = 0; mf < 2; ++mf) {
            const int row = m0 + wr * 32 + mf * 16 + lg * 4;
#pragma unroll
            for (int nf = 0; nf < 4; ++nf) {
                const int col = n0 + wc * 64 + nf * 16 + lr;
#pragma unroll
                for (int i = 0; i < 4; ++i)
                    outp[(size_t)(row + i) * N + col] = acc[mf][nf][i];
            }
        }
    } else {
#pragma unroll
        for (int mf = 0; mf < 2; ++mf) {
            const int row = m0 + wr * 32 + mf * 16 + lg * 4;
            const int b   = row >> 11;
            const int tt0 = row & (SEQ - 1);
#pragma unroll
            for (int nf = 0; nf < 4; ++nf) {
                const int col   = n0 + wc * 64 + nf * 16 + lr;
                const int which = col >> 10;
                const int h     = (col >> 6) & 15;
                const int d     = col & 63;
                if (which == 2) {
                    ushort* p = Vw + (((size_t)(b * NH + h) * HD + d) * SEQ) + tt0;
                    alignas(8) ushort e4[4];
#pragma unroll
                    for (int i = 0; i < 4; ++i) e4[i] = f2h(acc[mf][nf][i]);
                    *(uint2*)p = *(const uint2*)e4;
                } else {
                    ushort* dst = (which == 0) ? Qw : Kw;
                    const float sc = (which == 0) ? QSCALE : 1.0f;
#pragma unroll
                    for (int i = 0; i < 4; ++i)
                        dst[((size_t)(b * NH + h) * SEQ + tt0 + i) * HD + d] =
                            f2h(acc[mf][nf][i] * sc);
                }
            }
        }
    }
}

// ---------------------------------------------------------------------------
// Split-K swapped-operand MFMA flash attention, v10 = v7 (proven, 56.2 us)
// with loop-invariant LDS addressing:
//   swz = ((kb*32+q)&7)<<4 = (q&7)<<4  (kb-independent since 32%8==0)
//   addr = group_base + po[kc] + kb*4096 + BUF*8192,
//   po[kc] = q*128 + ((kc*32+hi*16) ^ ((q&7)<<4))   (4 regs, hoisted)
// KV loop unrolled x2 with LITERAL buffer indices (kills runtime `cur`
// selects; kb*4096+BUF*8192 folds into the ds_read immediate).
// Identical bytes read, identical op order -> bitwise-identical output.
// Block = 512 threads = 2 wave-groups x 4 waves; group g owns keys
// [g*1024,(g+1)*1024); in-block LDS split-K combine; bh-clustered swizzle.
// C/D layout (m74/m101): col=lane&31, row=(reg&3)+8*(reg>>2)+4*(lane>>5).
// ---------------------------------------------------------------------------
__global__ __launch_bounds__(512, 4)
void attn_mfma10(const ushort* __restrict__ Qw, const ushort* __restrict__ Kw,
                 const ushort* __restrict__ Vtg, ushort* __restrict__ AO)
{
    __shared__ ushort KsAll[2][2][64 * 64];   // [group][buf] 32 KB
    __shared__ ushort VtAll[2][2][64 * 64];   // [group][buf] 32 KB, V^T swizzled

    const int t    = threadIdx.x;
    const int w    = t >> 6;     // 0..7
    const int l    = t & 63;
    const int q    = l & 31;     // lane's q column
    const int hi   = l >> 5;     // 0/1
    const int half = w >> 2;     // KV half
    const int ww   = w & 3;      // wave-in-group

    // T1: bh-clustered XCD swizzle (512 = 8 x 64, bijective)
    const int lin = blockIdx.y * 16 + blockIdx.x;
    const int id2 = (lin & 7) * 64 + (lin >> 3);
    const int bh  = id2 >> 4;
    const int q0  = (id2 & 15) * 128 + ww * 32;

    const int kbase = half * (SEQ / 2);
    const int NT = (SEQ / 2) / 64;   // 16 tiles per group (even)

    const ushort* Qp = Qw  + (size_t)bh * SEQ * HD;
    const ushort* Kp = Kw  + (size_t)bh * SEQ * HD;
    const ushort* Vp = Vtg + (size_t)bh * HD * SEQ;   // [d][key] d-major

    ushort (*Ks)[64 * 64] = KsAll[half];
    ushort (*Vt)[64 * 64] = VtAll[half];
    const char* ksb = (const char*)KsAll[half];
    const char* vtb = (const char*)VtAll[half];

    // hoisted per-lane fragment offsets (loop-invariant)
    uint po[4];
#pragma unroll
    for (int kc = 0; kc < 4; ++kc)
        po[kc] = (uint)(q * 128 + ((kc * 32 + hi * 16) ^ ((q & 7) << 4)));

    // Q B-frags: qf[kc] = Q[q0+q][kc*16 + hi*8 + (0..7)]
    f16x8 qf[4];
#pragma unroll
    for (int kc = 0; kc < 4; ++kc)
        qf[kc] = *(const f16x8*)(Qp + (size_t)(q0 + q) * HD + kc * 16 + hi * 8);

    f32x16 oacc[2];
#pragma unroll
    for (int db = 0; db < 2; ++db)
#pragma unroll
        for (int r = 0; r < 16; ++r) oacc[db][r] = 0.f;
    float m_run = -3.0e38f, l_run = 0.f;

    f32x16 z16;                         // persistent zero C-operand
#pragma unroll
    for (int r = 0; r < 16; ++r) z16[r] = 0.f;

    // staging: linear dest, inverse-swizzled source (proven pattern).
    auto stageK = [&](int buf, int k0) {
#pragma unroll
        for (int s = 0; s < 2; ++s) {
            const int c    = ww * 64 + l + 256 * s;
            const int row  = c >> 3;
            const int unit = (c & 7) ^ (row & 7);
            gload_lds16(Kp + (size_t)(k0 + row) * HD + unit * 8,
                        &Ks[buf][(ww * 64 + 256 * s) * 8]);
        }
    };
    auto stageV = [&](int buf, int k0) {
#pragma unroll
        for (int s = 0; s < 2; ++s) {
            const int c    = ww * 64 + l + 256 * s;
            const int row  = c >> 3;                 // d row
            const int unit = (c & 7) ^ (row & 7);
            gload_lds16(Vp + (size_t)row * SEQ + k0 + unit * 8,
                        &Vt[buf][(ww * 64 + 256 * s) * 8]);
        }
    };

    // one KV tile with LITERAL buffer index (constant-folds after inlining)
    auto tile = [&](int BUF, int kt) {
        if (kt + 1 < NT) {               // issue next-tile DMA before compute
            stageK(BUF ^ 1, kbase + (kt + 1) * 64);
            stageV(BUF ^ 1, kbase + (kt + 1) * 64);
        }

        // ---- S^T = K . Q^T ----
        f32x16 sacc[2];
        __builtin_amdgcn_s_setprio(1);
#pragma unroll
        for (int kb = 0; kb < 2; ++kb) {
            const char* base = ksb + BUF * 8192 + kb * 4096;
            f16x8 kf0 = *(const f16x8*)(base + po[0]);
            f32x16 a = __builtin_amdgcn_mfma_f32_32x32x16_f16(kf0, qf[0], z16, 0, 0, 0);
#pragma unroll
            for (int kc = 1; kc < 4; ++kc) {
                f16x8 kf = *(const f16x8*)(base + po[kc]);
                a = __builtin_amdgcn_mfma_f32_32x32x16_f16(kf, qf[kc], a, 0, 0, 0);
            }
            sacc[kb] = a;
        }
        __builtin_amdgcn_s_setprio(0);

        // ---- in-lane online softmax (exp2), max3 tree + defer-max ----
        float p0 = fmax3(fmaxf(sacc[0][0], sacc[1][0]),
                         fmaxf(sacc[0][1], sacc[1][1]),
                         fmaxf(sacc[0][2], sacc[1][2]));
        float p1 = fmax3(fmaxf(sacc[0][3], sacc[1][3]),
                         fmaxf(sacc[0][4], sacc[1][4]),
                         fmaxf(sacc[0][5], sacc[1][5]));
        float p2 = fmax3(fmaxf(sacc[0][6], sacc[1][6]),
                         fmaxf(sacc[0][7], sacc[1][7]),
                         fmaxf(sacc[0][8], sacc[1][8]));
        float p3 = fmax3(fmaxf(sacc[0][9], sacc[1][9]),
                         fmaxf(sacc[0][10], sacc[1][10]),
                         fmaxf(sacc[0][11], sacc[1][11]));
        float p4 = fmax3(fmaxf(sacc[0][12], sacc[1][12]),
                         fmaxf(sacc[0][13], sacc[1][13]),
                         fmaxf(sacc[0][14], sacc[1][14]));
        float p5 = fmaxf(sacc[0][15], sacc[1][15]);
        float mx = fmaxf(fmax3(p0, p1, p2), fmax3(p3, p4, p5));
        mx = fmaxf(mx, __shfl_xor(mx, 32));   // combine partner half-row

        if (__any(mx > m_run + 8.0f)) {    // rescale only when max grew enough
            const float m_new = fmaxf(m_run, mx);
            const float scale = fexp2(m_run - m_new);
            m_run = m_new;
            l_run *= scale;
#pragma unroll
            for (int db = 0; db < 2; ++db)
#pragma unroll
                for (int r = 0; r < 16; ++r) oacc[db][r] *= scale;
        }

#pragma unroll
        for (int kb = 0; kb < 2; ++kb)
#pragma unroll
            for (int r = 0; r < 16; ++r)
                sacc[kb][r] = fexp2(sacc[kb][r] - m_run);

        float ts[16];
#pragma unroll
        for (int r = 0; r < 16; ++r) ts[r] = sacc[0][r] + sacc[1][r];
#pragma unroll
        for (int s = 8; s > 0; s >>= 1)
#pragma unroll
            for (int r = 0; r < 8; ++r)
                if (r < s) ts[r] += ts[r + s];
        l_run += ts[0] + __shfl_xor(ts[0], 32);

        // ---- pack P^T frags: cvt_pkrtz + permlane32_swap ----
        f16x8 pfrag[4];
#pragma unroll
        for (int kb = 0; kb < 2; ++kb)
#pragma unroll
            for (int lc = 0; lc < 2; ++lc) {
                const int rb = lc * 8;
                uint a = pkh(sacc[kb][rb + 0], sacc[kb][rb + 1]);
                uint b = pkh(sacc[kb][rb + 2], sacc[kb][rb + 3]);
                uint c = pkh(sacc[kb][rb + 4], sacc[kb][rb + 5]);
                uint d = pkh(sacc[kb][rb + 6], sacc[kb][rb + 7]);
                uivec2 r0 = __builtin_amdgcn_permlane32_swap(a, c, false, false);
                uivec2 r1 = __builtin_amdgcn_permlane32_swap(b, d, false, false);
                union { uint u[4]; f16x8 v; } f;
                f.u[0] = r0.x;
                f.u[1] = r1.x;
                f.u[2] = r0.y;
                f.u[3] = r1.y;
                pfrag[kb * 2 + lc] = f.v;
            }

        // ---- O^T += V^T . P^T  (proven swizzled ds_read_b128 path) ----
        __builtin_amdgcn_s_setprio(1);
#pragma unroll
        for (int db = 0; db < 2; ++db) {
            const char* base = vtb + BUF * 8192 + db * 4096;
#pragma unroll
            for (int kc = 0; kc < 4; ++kc) {
                f16x8 vf = *(const f16x8*)(base + po[kc]);
                oacc[db] = __builtin_amdgcn_mfma_f32_32x32x16_f16(
                    vf, pfrag[kc], oacc[db], 0, 0, 0);
            }
        }
        __builtin_amdgcn_s_setprio(0);

        __syncthreads();
    };

    stageK(0, kbase);
    stageV(0, kbase);
    __syncthreads();

#pragma unroll 1
    for (int it = 0; it < NT; it += 2) {   // NT even; literal buffer indices
        tile(0, it);
        tile(1, it + 1);
    }

    // ---- in-block split-K combine (reuse retired K/V LDS) ----
    float* oex = (float*)KsAll;            // [4][2][16][64] f32 = 32 KB
    float* mex = (float*)VtAll;            // [4][64]
    float* lex = mex + 256;                // [4][64]

    if (half == 1) {
        mex[ww * 64 + l] = m_run;
        lex[ww * 64 + l] = l_run;
#pragma unroll
        for (int db = 0; db < 2; ++db)
#pragma unroll
            for (int r = 0; r < 16; ++r)
                oex[(((ww * 2 + db) * 16) + r) * 64 + l] = oacc[db][r];
    }
    __syncthreads();
    if (half == 0) {
        const float m2 = mex[ww * 64 + l];
        const float l2 = lex[ww * 64 + l];
        const float mf = fmaxf(m_run, m2);
        float w1 = fexp2(m_run - mf), w2 = fexp2(m2 - mf);
        const float inv = 1.f / (l_run * w1 + l2 * w2);
        w1 *= inv; w2 *= inv;

        const int b = bh >> 4, h = bh & 15;
        ushort* orow = AO + ((size_t)(b * SEQ) + q0 + q) * D_MODEL + h * HD;
#pragma unroll
        for (int db = 0; db < 2; ++db)
#pragma unroll
            for (int g = 0; g < 4; ++g) {
                const int d = db * 32 + g * 8 + hi * 4;
                alignas(8) ushort e4[4];
#pragma unroll
                for (int i = 0; i < 4; ++i) {
                    const float o2 = oex[(((ww * 2 + db) * 16) + g * 4 + i) * 64 + l];
                    e4[i] = f2h(oacc[db][g * 4 + i] * w1 + o2 * w2);
                }
                *(uint2*)(orow + d) = *(const uint2*)e4;
            }
    }
}

// ---------------------------------------------------------------------------
extern "C" void kernel_launch(void* const* d_in, const int* in_sizes, int n_in,
                              void* d_out, int out_size, void* d_ws, size_t ws_size,
                              hipStream_t stream)
{
    const float* x      = (const float*)d_in[0];  // (2, 2048, 1024)
    const float* w_qkv  = (const float*)d_in[1];  // (1024, 3072)
    const float* w_proj = (const float*)d_in[2];  // (1024, 1024)
    float* out = (float*)d_out;                   // (2, 2048, 1024) fp32

    ushort* Xh  = (ushort*)d_ws;                        // 4M
    ushort* WqT = Xh  + (size_t)MTOT * D_MODEL;         // 3M  [3072][1024]
    ushort* WpT = WqT + (size_t)3 * D_MODEL * D_MODEL;  // 1M  [1024][1024]
    ushort* Qw  = WpT + (size_t)D_MODEL * D_MODEL;      // 4M  [B][H][T][64]
    ushort* Kw  = Qw  + (size_t)MTOT * D_MODEL;         // 4M  [B][H][T][64]
    ushort* Vt  = Kw  + (size_t)MTOT * D_MODEL;         // 4M  [B][H][64][T]
    ushort* AOh = Vt  + (size_t)MTOT * D_MODEL;         // 4M  [B][T][D]

    dim3 blk(256);

    // 0) fused prep: x cast + both weight transposes in one launch
    prep_fused<<<dim3(2048 + 3072 + 1024), blk, 0, stream>>>(
        x, w_qkv, w_proj, Xh, WqT, WpT);

    // 1) QKV = Xh @ WqT^T (64x128 tiles, 1536 blocks)
    gemm_mfma<0><<<dim3(3 * D_MODEL / 128, MTOT / 64), blk, 0, stream>>>(
        Xh, WqT, nullptr, Qw, Kw, Vt, 3 * D_MODEL);

    // 2) split-K MFMA flash attention (hoisted addressing, unrolled x2)
    attn_mfma10<<<dim3(SEQ / 128, BSZ * NH), dim3(512), 0, stream>>>(Qw, Kw, Vt, AOh);

    // 3) out = AOh @ WpT^T (fp32 out, 512 blocks)
    gemm_mfma<1><<<dim3(D_MODEL / 128, MTOT / 64), blk, 0, stream>>>(
        AOh, WpT, out, nullptr, nullptr, nullptr, D_MODEL);
}